// Round 14
// baseline (407.083 us; speedup 1.0000x reference)
//
#include <hip/hip_runtime.h>
#include <math.h>

static constexpr int NB = 16;
static constexpr int NC = 3;
static constexpr int IM = 224;
static constexpr int IMP = IM * IM;      // 50176
static constexpr int HPq = 14;
static constexpr int NPq = 196;
static constexpr int OUTq = 1024;
static constexpr int DIq = 1536;
static constexpr int ROWS = NB * NPq;    // 3136
static constexpr int MPAD = 3200;        // 25*128, GEMM A-operand row padding

typedef __bf16 bf8_t __attribute__((ext_vector_type(8)));
typedef float f4_t __attribute__((ext_vector_type(4)));
typedef unsigned short us8 __attribute__((ext_vector_type(8)));
typedef const __attribute__((address_space(1))) unsigned int cgu32;
typedef __attribute__((address_space(3))) unsigned int lu32;

__device__ inline unsigned short f2bf(float x) {
    unsigned u = __builtin_bit_cast(unsigned, x);
    unsigned r = (u + 0x7FFFu + ((u >> 16) & 1u)) >> 16;
    return (unsigned short)r;
}
__device__ inline float bf2f(unsigned short v) {
    return __builtin_bit_cast(float, (unsigned)v << 16);
}
__device__ inline float fast_sig(float x) {
    return __builtin_amdgcn_rcpf(1.f + __expf(-x));
}
__device__ inline float fast_softplus(float v) {
    return fmaxf(v, 0.f) + __logf(1.f + __expf(-fabsf(v)));
}

template<int CTRL>
__device__ inline float dpp_add(float x) {
    int v = __builtin_amdgcn_update_dpp(0, __builtin_bit_cast(int, x), CTRL, 0xF, 0xF, true);
    return x + __builtin_bit_cast(float, v);
}

// ---------------- K1a: channel avg/max ----------------
__global__ __launch_bounds__(256) void k_avgmax(const float* __restrict__ img, float* __restrict__ am) {
    int idx = blockIdx.x * 256 + threadIdx.x;
    if (idx >= NB * IMP / 4) return;
    int p4 = (idx % (IMP / 4)) * 4, b = idx / (IMP / 4);
    const float* ib = img + (size_t)b * NC * IMP + p4;
    float4 c0 = *(const float4*)ib;
    float4 c1 = *(const float4*)(ib + IMP);
    float4 c2 = *(const float4*)(ib + 2 * IMP);
    float4 av, mx;
    av.x = (c0.x + c1.x + c2.x) * (1.f / 3.f); mx.x = fmaxf(c0.x, fmaxf(c1.x, c2.x));
    av.y = (c0.y + c1.y + c2.y) * (1.f / 3.f); mx.y = fmaxf(c0.y, fmaxf(c1.y, c2.y));
    av.z = (c0.z + c1.z + c2.z) * (1.f / 3.f); mx.z = fmaxf(c0.z, fmaxf(c1.z, c2.z));
    av.w = (c0.w + c1.w + c2.w) * (1.f / 3.f); mx.w = fmaxf(c0.w, fmaxf(c1.w, c2.w));
    *(float4*)(am + (size_t)(b * 2 + 0) * IMP + p4) = av;
    *(float4*)(am + (size_t)(b * 2 + 1) * IMP + p4) = mx;
}

// ---------------- K1b: 7x7 conv gate + patchify ----------------
__global__ __launch_bounds__(256) void k_gatepatch(const float* __restrict__ img, const float* __restrict__ am,
                                                   const float* __restrict__ saw, unsigned short* __restrict__ G) {
    int quad = blockIdx.x * 256 + threadIdx.x;
    if (quad >= NB * IMP / 4) return;
    int pq = quad % (IMP / 4), b = quad / (IMP / 4);
    int x0 = (pq % 56) * 4;
    int y = pq / 56;
    float acc0 = 0.f, acc1 = 0.f, acc2 = 0.f, acc3 = 0.f;
    const bool lok = (x0 >= 4), rok = (x0 <= IM - 8);
    #pragma unroll
    for (int ci = 0; ci < 2; ci++) {
        const float* amc = am + (size_t)(b * 2 + ci) * IMP;
        const float* wc = saw + ci * 49;
        #pragma unroll
        for (int kh = 0; kh < 7; kh++) {
            int yy = y + kh - 3;
            if (yy < 0 || yy >= IM) continue;
            const float* rowp = amc + yy * IM;
            float4 lv = lok ? *(const float4*)(rowp + x0 - 4) : make_float4(0.f, 0.f, 0.f, 0.f);
            float4 mv = *(const float4*)(rowp + x0);
            float4 rv = rok ? *(const float4*)(rowp + x0 + 4) : make_float4(0.f, 0.f, 0.f, 0.f);
            float f[12] = {lv.x, lv.y, lv.z, lv.w, mv.x, mv.y, mv.z, mv.w, rv.x, rv.y, rv.z, rv.w};
            #pragma unroll
            for (int kw = 0; kw < 7; kw++) {
                float w = wc[kh * 7 + kw];
                acc0 = fmaf(w, f[kw + 1], acc0);
                acc1 = fmaf(w, f[kw + 2], acc1);
                acc2 = fmaf(w, f[kw + 3], acc2);
                acc3 = fmaf(w, f[kw + 4], acc3);
            }
        }
    }
    float s0 = fast_sig(acc0), s1 = fast_sig(acc1), s2 = fast_sig(acc2), s3 = fast_sig(acc3);
    const float* ib = img + (size_t)b * NC * IMP + y * IM + x0;
    float4 c0 = *(const float4*)ib;
    float4 c1 = *(const float4*)(ib + IMP);
    float4 c2 = *(const float4*)(ib + 2 * IMP);
    int hy = y >> 4, py = y & 15, hx = x0 >> 4, px0 = x0 & 15;
    size_t base = ((size_t)(b * NPq + hy * HPq + hx) * 768) + (size_t)(py * 16 + px0) * 3;
    ushort4 o0, o1, o2;
    o0.x = f2bf(c0.x * s0); o0.y = f2bf(c1.x * s0); o0.z = f2bf(c2.x * s0);
    o0.w = f2bf(c0.y * s1);
    o1.x = f2bf(c1.y * s1); o1.y = f2bf(c2.y * s1);
    o1.z = f2bf(c0.z * s2); o1.w = f2bf(c1.z * s2);
    o2.x = f2bf(c2.z * s2);
    o2.y = f2bf(c0.w * s3); o2.z = f2bf(c1.w * s3); o2.w = f2bf(c2.w * s3);
    *(ushort4*)(G + base + 0) = o0;
    *(ushort4*)(G + base + 4) = o1;
    *(ushort4*)(G + base + 8) = o2;
}

// ---------------- all weight transposes + xproj pad, ONE launch ----------------
// ranges: pe 576 | in0 2880 | in1 5184 | ot0 6336 | ot1 7488 | em 8256 | at 9280 | xpw 10816
__global__ __launch_bounds__(256) void k_transpose_all(const float* pe_w, const float* in_w, const float* ot_w,
                                                       const float* em_w, const float* at_w, const float* xp_w,
                                                       unsigned short* wpe, unsigned short* win0, unsigned short* win1,
                                                       unsigned short* wot0, unsigned short* wot1,
                                                       unsigned short* wem, unsigned short* wat,
                                                       unsigned short* xpt) {
    int bid = blockIdx.x;
    if (bid >= 9280) {
        int idx = (bid - 9280) * 256 + threadIdx.x;
        int k = idx % 1536;
        int n = (idx / 1536) % 128;
        int l = idx / (1536 * 128);
        unsigned short v = 0;
        if (n < 80) v = f2bf(xp_w[(size_t)l * 1536 * 80 + (size_t)k * 80 + n]);
        xpt[idx] = v;
        return;
    }
    const float* W; unsigned short* Wt; int K, N, local;
    if (bid < 576)       { W = pe_w; Wt = wpe; K = 768; N = 768; local = bid; }
    else if (bid < 2880) { W = in_w; Wt = win0; K = 768; N = 3072; local = bid - 576; }
    else if (bid < 5184) { W = in_w + (size_t)768 * 3072; Wt = win1; K = 768; N = 3072; local = bid - 2880; }
    else if (bid < 6336) { W = ot_w; Wt = wot0; K = 1536; N = 768; local = bid - 5184; }
    else if (bid < 7488) { W = ot_w + (size_t)1536 * 768; Wt = wot1; K = 1536; N = 768; local = bid - 6336; }
    else if (bid < 8256) { W = em_w; Wt = wem; K = 768; N = 1024; local = bid - 7488; }
    else                 { W = at_w; Wt = wat; K = 1024; N = 1024; local = bid - 8256; }
    int gx = N / 32;
    int n0 = (local % gx) * 32, k0 = (local / gx) * 32;
    __shared__ float t[32][33];
    int c = threadIdx.x & 31, r8 = threadIdx.x >> 5;
    #pragma unroll
    for (int i = 0; i < 4; i++) {
        int r = r8 + i * 8;
        t[r][c] = W[(size_t)(k0 + r) * N + n0 + c];
    }
    __syncthreads();
    #pragma unroll
    for (int i = 0; i < 4; i++) {
        int r = r8 + i * 8;
        Wt[(size_t)(n0 + r) * K + k0 + c] = f2bf(t[c][r]);
    }
}

// ---------------- bf16 MFMA GEMM, BN=64 double-buffered (general shapes) ----------------
enum { EPI_NONE = 0, EPI_POSEMB = 1 };

template<int EPI, bool CBF>
__global__ __launch_bounds__(256) void k_gemm_bf(const unsigned short* __restrict__ A,
                                                 const unsigned short* __restrict__ Wt,
                                                 const float* __restrict__ bias,
                                                 void* __restrict__ Cv, int ldc,
                                                 int M, int N, int K,
                                                 const float* __restrict__ extra) {
    constexpr int BM = 128, BN = 64;
    __shared__ __align__(16) unsigned short As[2][BM * 64];
    __shared__ __align__(16) unsigned short Bs[2][BN * 64];
    const int bm = blockIdx.y * BM, bn = blockIdx.x * BN;
    const int tid = threadIdx.x;
    const int lane = tid & 63;
    const int wbase = tid & ~63;
    const int wr = ((tid >> 7) & 1) * 64;
    const int wc = ((tid >> 6) & 1) * 32;
    const int lr = lane & 15, lq = lane >> 4;

    f4_t acc[4][2] = {};

    auto stage = [&](int buf, int k0) {
        #pragma unroll
        for (int i = 0; i < 4; i++) {
            int gid2 = i * 256 + tid;
            int r = gid2 >> 3, g = gid2 & 7;
            const unsigned short* src = A + (size_t)(bm + r) * K + k0 + ((g ^ (r & 7)) * 8);
            __builtin_amdgcn_global_load_lds((cgu32*)src,
                (lu32*)&As[buf][(i * 256 + wbase) * 8], 16, 0, 0);
        }
        #pragma unroll
        for (int i = 0; i < 2; i++) {
            int gid2 = i * 256 + tid;
            int r = gid2 >> 3, g = gid2 & 7;
            const unsigned short* src = Wt + (size_t)(bn + r) * K + k0 + ((g ^ (r & 7)) * 8);
            __builtin_amdgcn_global_load_lds((cgu32*)src,
                (lu32*)&Bs[buf][(i * 256 + wbase) * 8], 16, 0, 0);
        }
    };

    stage(0, 0);
    __syncthreads();
    int cur = 0;
    for (int k0 = 0; k0 < K; k0 += 64) {
        if (k0 + 64 < K) stage(cur ^ 1, k0 + 64);
        #pragma unroll
        for (int h = 0; h < 2; h++) {
            bf8_t af[4], bfr[2];
            #pragma unroll
            for (int mb = 0; mb < 4; mb++) {
                int row = wr + mb * 16 + lr;
                int g = h * 4 + lq;
                af[mb] = *(const bf8_t*)&As[cur][row * 64 + ((g ^ (row & 7)) * 8)];
            }
            #pragma unroll
            for (int nb = 0; nb < 2; nb++) {
                int rn = wc + nb * 16 + lr;
                int g = h * 4 + lq;
                bfr[nb] = *(const bf8_t*)&Bs[cur][rn * 64 + ((g ^ (rn & 7)) * 8)];
            }
            #pragma unroll
            for (int mb = 0; mb < 4; mb++)
                #pragma unroll
                for (int nb = 0; nb < 2; nb++)
                    acc[mb][nb] = __builtin_amdgcn_mfma_f32_16x16x32_bf16(af[mb], bfr[nb], acc[mb][nb], 0, 0, 0);
        }
        __syncthreads();
        cur ^= 1;
    }

    #pragma unroll
    for (int mb = 0; mb < 4; mb++) {
        #pragma unroll
        for (int nb = 0; nb < 2; nb++) {
            int col = bn + wc + nb * 16 + lr;
            #pragma unroll
            for (int q = 0; q < 4; q++) {
                int row = bm + wr + mb * 16 + lq * 4 + q;
                if (row < M) {
                    float v = acc[mb][nb][q];
                    if (bias) v += bias[col];
                    if (EPI == EPI_POSEMB) v += extra[(size_t)(row % NPq) * N + col];
                    if (CBF) ((unsigned short*)Cv)[(size_t)row * ldc + col] = f2bf(v);
                    else     ((float*)Cv)[(size_t)row * ldc + col] = v;
                }
            }
        }
    }
}

// ---------------- 128x128 single-buffer GEMM (m97 structure), split epilogue ----------------
__global__ __launch_bounds__(256) void k_gemm_bf2(const unsigned short* __restrict__ A,
                                                  const unsigned short* __restrict__ Wt,
                                                  const float* __restrict__ bias,
                                                  unsigned short* __restrict__ xr2,
                                                  unsigned short* __restrict__ sres,
                                                  int M, int K) {
    constexpr int BM = 128;
    __shared__ __align__(16) unsigned short As[BM * 64];
    __shared__ __align__(16) unsigned short Bs[BM * 64];
    const int bm = blockIdx.y * BM, bn = blockIdx.x * BM;
    const int tid = threadIdx.x;
    const int lane = tid & 63;
    const int wbase = tid & ~63;
    const int wid = tid >> 6;
    const int wr = (wid >> 1) * 64;
    const int wc = (wid & 1) * 64;
    const int lr = lane & 15, lq = lane >> 4;

    f4_t acc[4][4] = {};

    for (int k0 = 0; k0 < K; k0 += 64) {
        #pragma unroll
        for (int i = 0; i < 4; i++) {
            int gid2 = i * 256 + tid;
            int r = gid2 >> 3, g = gid2 & 7;
            const unsigned short* srcA = A + (size_t)(bm + r) * K + k0 + ((g ^ (r & 7)) * 8);
            __builtin_amdgcn_global_load_lds((cgu32*)srcA,
                (lu32*)&As[(i * 256 + wbase) * 8], 16, 0, 0);
            const unsigned short* srcB = Wt + (size_t)(bn + r) * K + k0 + ((g ^ (r & 7)) * 8);
            __builtin_amdgcn_global_load_lds((cgu32*)srcB,
                (lu32*)&Bs[(i * 256 + wbase) * 8], 16, 0, 0);
        }
        __syncthreads();
        #pragma unroll
        for (int h = 0; h < 2; h++) {
            bf8_t af[4], bfr[4];
            #pragma unroll
            for (int mb = 0; mb < 4; mb++) {
                int row = wr + mb * 16 + lr;
                int g = h * 4 + lq;
                af[mb] = *(const bf8_t*)&As[row * 64 + ((g ^ (row & 7)) * 8)];
            }
            #pragma unroll
            for (int nb = 0; nb < 4; nb++) {
                int rn = wc + nb * 16 + lr;
                int g = h * 4 + lq;
                bfr[nb] = *(const bf8_t*)&Bs[rn * 64 + ((g ^ (rn & 7)) * 8)];
            }
            #pragma unroll
            for (int mb = 0; mb < 4; mb++)
                #pragma unroll
                for (int nb = 0; nb < 4; nb++)
                    acc[mb][nb] = __builtin_amdgcn_mfma_f32_16x16x32_bf16(af[mb], bfr[nb], acc[mb][nb], 0, 0, 0);
        }
        __syncthreads();
    }

    #pragma unroll
    for (int mb = 0; mb < 4; mb++) {
        #pragma unroll
        for (int nb = 0; nb < 4; nb++) {
            int col = bn + wc + nb * 16 + lr;
            float bv = bias[col];
            #pragma unroll
            for (int q = 0; q < 4; q++) {
                int row = bm + wr + mb * 16 + lq * 4 + q;
                if (row < M) {
                    float v = acc[mb][nb][q] + bv;
                    if (col < DIq) xr2[(size_t)row * DIq + col] = f2bf(v);
                    else           sres[(size_t)row * DIq + (col - DIq)] = f2bf(v * fast_sig(v));
                }
            }
        }
    }
}

// ---------------- dt GEMM (K=48) + fast softplus; reads dbc128 directly ----------------
static constexpr int DT_RPB = 4;
__global__ __launch_bounds__(384) void k_dtred(const float* __restrict__ dbc128, const float* __restrict__ W,
                                               const float* __restrict__ bias, float* __restrict__ de) {
    int r0 = blockIdx.x * DT_RPB;
    int tid = threadIdx.x;
    __shared__ float ds[DT_RPB][48];
    if (tid < DT_RPB * 48) {
        int row = tid / 48, col = tid % 48;
        ds[row][col] = dbc128[(size_t)(r0 + row) * 128 + col];
    }
    __syncthreads();
    int j = tid * 4;
    float4 b = *(const float4*)(bias + j);
    float4 a0 = b, a1 = b, a2 = b, a3 = b;
    for (int k = 0; k < 48; k++) {
        float4 w = *(const float4*)(W + (size_t)k * 1536 + j);
        float d0 = ds[0][k], d1 = ds[1][k], d2 = ds[2][k], d3 = ds[3][k];
        a0.x = fmaf(d0, w.x, a0.x); a0.y = fmaf(d0, w.y, a0.y); a0.z = fmaf(d0, w.z, a0.z); a0.w = fmaf(d0, w.w, a0.w);
        a1.x = fmaf(d1, w.x, a1.x); a1.y = fmaf(d1, w.y, a1.y); a1.z = fmaf(d1, w.z, a1.z); a1.w = fmaf(d1, w.w, a1.w);
        a2.x = fmaf(d2, w.x, a2.x); a2.y = fmaf(d2, w.y, a2.y); a2.z = fmaf(d2, w.z, a2.z); a2.w = fmaf(d2, w.w, a2.w);
        a3.x = fmaf(d3, w.x, a3.x); a3.y = fmaf(d3, w.y, a3.y); a3.z = fmaf(d3, w.z, a3.z); a3.w = fmaf(d3, w.w, a3.w);
    }
    float4 o;
    o.x = fast_softplus(a0.x); o.y = fast_softplus(a0.y); o.z = fast_softplus(a0.z); o.w = fast_softplus(a0.w);
    *(float4*)(de + (size_t)(r0 + 0) * 1536 + j) = o;
    o.x = fast_softplus(a1.x); o.y = fast_softplus(a1.y); o.z = fast_softplus(a1.z); o.w = fast_softplus(a1.w);
    *(float4*)(de + (size_t)(r0 + 1) * 1536 + j) = o;
    o.x = fast_softplus(a2.x); o.y = fast_softplus(a2.y); o.z = fast_softplus(a2.z); o.w = fast_softplus(a2.w);
    *(float4*)(de + (size_t)(r0 + 2) * 1536 + j) = o;
    o.x = fast_softplus(a3.x); o.y = fast_softplus(a3.y); o.z = fast_softplus(a3.z); o.w = fast_softplus(a3.w);
    *(float4*)(de + (size_t)(r0 + 3) * 1536 + j) = o;
}

// ---------------- causal depthwise conv (DC=4) + silu, bf16 in/out ----------------
__global__ __launch_bounds__(256) void k_conv_silu(const unsigned short* __restrict__ xr2, const float* __restrict__ cw,
                                                   const float* __restrict__ cb, unsigned short* __restrict__ xi2b) {
    int idx4 = blockIdx.x * 256 + threadIdx.x;
    if (idx4 >= ROWS * DIq / 4) return;
    int d4 = (idx4 % (DIq / 4)) * 4;
    int bt = idx4 / (DIq / 4);
    int t = bt % NPq, b = bt / NPq;
    const unsigned short* base = xr2 + (size_t)b * NPq * DIq + d4;
    float4 s = *(const float4*)(cb + d4);
    float4 w0 = *(const float4*)(cw + (d4 + 0) * 4);
    float4 w1 = *(const float4*)(cw + (d4 + 1) * 4);
    float4 w2 = *(const float4*)(cw + (d4 + 2) * 4);
    float4 w3 = *(const float4*)(cw + (d4 + 3) * 4);
    if (t >= 3) {
        ushort4 v = *(const ushort4*)(base + (size_t)(t - 3) * DIq);
        s.x = fmaf(bf2f(v.x), w0.x, s.x); s.y = fmaf(bf2f(v.y), w1.x, s.y);
        s.z = fmaf(bf2f(v.z), w2.x, s.z); s.w = fmaf(bf2f(v.w), w3.x, s.w);
    }
    if (t >= 2) {
        ushort4 v = *(const ushort4*)(base + (size_t)(t - 2) * DIq);
        s.x = fmaf(bf2f(v.x), w0.y, s.x); s.y = fmaf(bf2f(v.y), w1.y, s.y);
        s.z = fmaf(bf2f(v.z), w2.y, s.z); s.w = fmaf(bf2f(v.w), w3.y, s.w);
    }
    if (t >= 1) {
        ushort4 v = *(const ushort4*)(base + (size_t)(t - 1) * DIq);
        s.x = fmaf(bf2f(v.x), w0.z, s.x); s.y = fmaf(bf2f(v.y), w1.z, s.y);
        s.z = fmaf(bf2f(v.z), w2.z, s.z); s.w = fmaf(bf2f(v.w), w3.z, s.w);
    }
    {
        ushort4 v = *(const ushort4*)(base + (size_t)t * DIq);
        s.x = fmaf(bf2f(v.x), w0.w, s.x); s.y = fmaf(bf2f(v.y), w1.w, s.y);
        s.z = fmaf(bf2f(v.z), w2.w, s.z); s.w = fmaf(bf2f(v.w), w3.w, s.w);
    }
    ushort4 xo;
    xo.x = f2bf(s.x * fast_sig(s.x)); xo.y = f2bf(s.y * fast_sig(s.y));
    xo.z = f2bf(s.z * fast_sig(s.z)); xo.w = f2bf(s.w * fast_sig(s.w));
    *(ushort4*)(xi2b + (size_t)bt * DIq + d4) = xo;
}

// ---------------- selective-scan, LDS double-buffered, packed b64 sdu, raw v_exp ----------------
static constexpr int STB = 28;

__global__ __launch_bounds__(256) void k_scan(const float* __restrict__ delta, const unsigned short* __restrict__ xi2b,
                                              const float* __restrict__ dbc128, const unsigned short* __restrict__ sresb,
                                              const float* __restrict__ Alog, const float* __restrict__ Dv,
                                              unsigned short* __restrict__ ys) {
    const int b = blockIdx.x;
    const int d0 = blockIdx.y * 32;
    const int tid = threadIdx.x;
    const int dl = tid >> 3;
    const int np = tid & 7;
    const int d = d0 + dl;
    const float A0p = -__expf(Alog[d * 16 + np]) * 1.44269504089f;
    const float A1p = -__expf(Alog[d * 16 + np + 8]) * 1.44269504089f;
    const float Dd = Dv[d];
    const int tr = tid >> 5;
    const int dls = tid & 31;

    __shared__ float2 sdu[2][STB][32];
    __shared__ float sbc[2][STB][32];

    const float* gde = delta + ((size_t)b * NPq + tr) * DIq + d0 + dls;
    const unsigned short* gu  = xi2b  + ((size_t)b * NPq + tr) * DIq + d0 + dls;
    const unsigned short* gsr = sresb + ((size_t)b * NPq + tr) * DIq + d0 + dls;
    const float* gbc = dbc128 + ((size_t)b * NPq + tr) * 128 + 48 + dls;
    unsigned short* gy = ys + (size_t)b * NPq * DIq + d;

    float rde[4], rbc[4];
    unsigned short ruu[4], rss[4];

    auto stageLoad = [&](int c) {
        const int t0 = c * STB;
        #pragma unroll
        for (int j = 0; j < 3; j++) {
            int off = (t0 + 8 * j) * DIq;
            rde[j] = gde[off];
            ruu[j] = gu[off];
            rss[j] = gsr[off];
            rbc[j] = gbc[(t0 + 8 * j) * 128];
        }
        if (tid < 128) {
            int off = (t0 + 24) * DIq;
            rde[3] = gde[off];
            ruu[3] = gu[off];
            rss[3] = gsr[off];
            rbc[3] = gbc[(t0 + 24) * 128];
        }
    };
    auto stageWrite = [&](int buf) {
        const int pi = (dls & 7) * 4 + (dls >> 3);
        #pragma unroll
        for (int j = 0; j < 3; j++) {
            int t = tr + 8 * j;
            unsigned pk = ((unsigned)ruu[j] << 16) | rss[j];
            sdu[buf][t][dls] = make_float2(rde[j], __builtin_bit_cast(float, pk));
            sbc[buf][t][pi] = rbc[j];
        }
        if (tid < 128) {
            int t = tr + 24;
            unsigned pk = ((unsigned)ruu[3] << 16) | rss[3];
            sdu[buf][t][dls] = make_float2(rde[3], __builtin_bit_cast(float, pk));
            sbc[buf][t][pi] = rbc[3];
        }
    };

    stageLoad(0);
    stageWrite(0);
    __syncthreads();

    float h0 = 0.f, h1 = 0.f;
    int cur = 0;
    for (int c = 0; c < 7; c++) {
        if (c < 6) stageLoad(c + 1);
        #pragma unroll 14
        for (int t = 0; t < STB; t++) {
            float2 duv = sdu[cur][t][dl];
            float4 bc = *(const float4*)&sbc[cur][t][np * 4];
            unsigned bits = __builtin_bit_cast(unsigned, duv.y);
            float u  = __builtin_bit_cast(float, bits & 0xFFFF0000u);
            float sr = __builtin_bit_cast(float, bits << 16);
            float a0 = __builtin_amdgcn_exp2f(duv.x * A0p);
            float a1 = __builtin_amdgcn_exp2f(duv.x * A1p);
            float deu = duv.x * u;
            h0 = fmaf(a0, h0, deu * bc.x);
            h1 = fmaf(a1, h1, deu * bc.y);
            float p = fmaf(h1, bc.w, h0 * bc.z);
            p = dpp_add<0xB1>(p);
            p = dpp_add<0x4E>(p);
            p = dpp_add<0x141>(p);
            if (np == 0) gy[(size_t)(c * STB + t) * DIq] = f2bf(fmaf(Dd, u, p) * sr);
        }
        if (c < 6) stageWrite(cur ^ 1);
        __syncthreads();
        cur ^= 1;
    }
}

// ---------------- row LayerNorm (1024) + exact gelu; templated in/out dtype ----------------
template<bool IBF, bool OBF>
__global__ __launch_bounds__(256) void k_ln_gelu(const void* __restrict__ inv, const float* __restrict__ g,
                                                 const float* __restrict__ bt, void* __restrict__ outv) {
    int row = blockIdx.x;
    float4 v;
    if (IBF) {
        ushort4 u = ((const ushort4*)((const unsigned short*)inv + (size_t)row * OUTq))[threadIdx.x];
        v.x = bf2f(u.x); v.y = bf2f(u.y); v.z = bf2f(u.z); v.w = bf2f(u.w);
    } else {
        v = ((const float4*)((const float*)inv + (size_t)row * OUTq))[threadIdx.x];
    }
    float s = v.x + v.y + v.z + v.w;
    float ss = v.x * v.x + v.y * v.y + v.z * v.z + v.w * v.w;
    #pragma unroll
    for (int off = 32; off >= 1; off >>= 1) { s += __shfl_down(s, off); ss += __shfl_down(ss, off); }
    __shared__ float sh[10];
    int wid = threadIdx.x >> 6, lid = threadIdx.x & 63;
    if (lid == 0) { sh[wid] = s; sh[4 + wid] = ss; }
    __syncthreads();
    if (threadIdx.x == 0) {
        float S = sh[0] + sh[1] + sh[2] + sh[3], SS = sh[4] + sh[5] + sh[6] + sh[7];
        float m = S * (1.f / OUTq);
        float var = SS * (1.f / OUTq) - m * m;
        sh[8] = m; sh[9] = rsqrtf(var + 1e-5f);
    }
    __syncthreads();
    float m = sh[8], rst = sh[9];
    float4 gv = ((const float4*)g)[threadIdx.x];
    float4 bv = ((const float4*)bt)[threadIdx.x];
    float4 o;
    float y0 = (v.x - m) * rst * gv.x + bv.x; o.x = 0.5f * y0 * (1.f + erff(y0 * 0.70710678118f));
    float y1 = (v.y - m) * rst * gv.y + bv.y; o.y = 0.5f * y1 * (1.f + erff(y1 * 0.70710678118f));
    float y2 = (v.z - m) * rst * gv.z + bv.z; o.z = 0.5f * y2 * (1.f + erff(y2 * 0.70710678118f));
    float y3 = (v.w - m) * rst * gv.w + bv.w; o.w = 0.5f * y3 * (1.f + erff(y3 * 0.70710678118f));
    if (OBF) {
        ushort4 o4;
        o4.x = f2bf(o.x); o4.y = f2bf(o.y); o4.z = f2bf(o.z); o4.w = f2bf(o.w);
        ((ushort4*)((unsigned short*)outv + (size_t)row * OUTq))[threadIdx.x] = o4;
    } else {
        ((float4*)((float*)outv + (size_t)row * OUTq))[threadIdx.x] = o;
    }
}

// ---------------- column softmax + pool, 4-way t-split; bf16 logits + values ----------------
__global__ __launch_bounds__(256) void k_softpool(const unsigned short* __restrict__ gm,
                                                  const unsigned short* __restrict__ ym,
                                                  float* __restrict__ pooled) {
    int b = blockIdx.y;
    int jl = threadIdx.x & 63;
    int j = blockIdx.x * 64 + jl;
    int tc = threadIdx.x >> 6;
    const unsigned short* gb = gm + (size_t)b * NPq * OUTq + j;
    const unsigned short* yb = ym + (size_t)b * NPq * OUTq + j;
    int t0 = tc * 49;
    float m = -1e30f, s = 0.f, ps = 0.f;
    for (int t = t0; t < t0 + 49; t++) {
        float g = bf2f(gb[(size_t)t * OUTq]);
        float y = bf2f(yb[(size_t)t * OUTq]);
        float mn = fmaxf(m, g);
        float sc = __expf(m - mn);
        float e = __expf(g - mn);
        s = fmaf(s, sc, e);
        ps = fmaf(ps, sc, y * e);
        m = mn;
    }
    __shared__ float sm[4][64], ssum[4][64], sps[4][64];
    sm[tc][jl] = m; ssum[tc][jl] = s; sps[tc][jl] = ps;
    __syncthreads();
    if (tc == 0) {
        float m0 = sm[0][jl], m1 = sm[1][jl], m2 = sm[2][jl], m3 = sm[3][jl];
        float mt = fmaxf(fmaxf(m0, m1), fmaxf(m2, m3));
        float e0 = __expf(m0 - mt), e1 = __expf(m1 - mt);
        float e2 = __expf(m2 - mt), e3 = __expf(m3 - mt);
        float st = ssum[0][jl] * e0 + ssum[1][jl] * e1 + ssum[2][jl] * e2 + ssum[3][jl] * e3;
        float pt = sps[0][jl] * e0 + sps[1][jl] * e1 + sps[2][jl] * e2 + sps[3][jl] * e3;
        pooled[b * OUTq + j] = pt / st;
    }
}

// ---------------- final LayerNorm ----------------
__global__ __launch_bounds__(256) void k_final_ln(const float* __restrict__ p, const float* __restrict__ g,
                                                  const float* __restrict__ bt, float* __restrict__ out) {
    int row = blockIdx.x;
    const float* x = p + (size_t)row * OUTq;
    float4 v = ((const float4*)x)[threadIdx.x];
    float s = v.x + v.y + v.z + v.w;
    float ss = v.x * v.x + v.y * v.y + v.z * v.z + v.w * v.w;
    #pragma unroll
    for (int off = 32; off >= 1; off >>= 1) { s += __shfl_down(s, off); ss += __shfl_down(ss, off); }
    __shared__ float sh[10];
    int wid = threadIdx.x >> 6, lid = threadIdx.x & 63;
    if (lid == 0) { sh[wid] = s; sh[4 + wid] = ss; }
    __syncthreads();
    if (threadIdx.x == 0) {
        float S = sh[0] + sh[1] + sh[2] + sh[3], SS = sh[4] + sh[5] + sh[6] + sh[7];
        float m = S * (1.f / OUTq);
        float var = SS * (1.f / OUTq) - m * m;
        sh[8] = m; sh[9] = rsqrtf(var + 1e-5f);
    }
    __syncthreads();
    float m = sh[8], rst = sh[9];
    float4 gv = ((const float4*)g)[threadIdx.x];
    float4 bv = ((const float4*)bt)[threadIdx.x];
    float4 o;
    o.x = (v.x - m) * rst * gv.x + bv.x;
    o.y = (v.y - m) * rst * gv.y + bv.y;
    o.z = (v.z - m) * rst * gv.z + bv.z;
    o.w = (v.w - m) * rst * gv.w + bv.w;
    ((float4*)(out + (size_t)row * OUTq))[threadIdx.x] = o;
}

extern "C" void kernel_launch(void* const* d_in, const int* in_sizes, int n_in,
                              void* d_out, int out_size, void* d_ws, size_t ws_size,
                              hipStream_t stream) {
    const float* img   = (const float*)d_in[0];
    const float* sa_w  = (const float*)d_in[1];
    const float* pe_w  = (const float*)d_in[2];
    const float* pe_b  = (const float*)d_in[3];
    const float* pos   = (const float*)d_in[4];
    const float* in_w  = (const float*)d_in[5];
    const float* in_b  = (const float*)d_in[6];
    const float* cv_w  = (const float*)d_in[7];
    const float* cv_b  = (const float*)d_in[8];
    const float* xp_w  = (const float*)d_in[9];
    const float* dt_w  = (const float*)d_in[10];
    const float* dt_b  = (const float*)d_in[11];
    const float* Alog  = (const float*)d_in[12];
    const float* Dv    = (const float*)d_in[13];
    const float* ot_w  = (const float*)d_in[14];
    const float* ot_b  = (const float*)d_in[15];
    const float* em_w  = (const float*)d_in[16];
    const float* em_b  = (const float*)d_in[17];
    const float* em_g  = (const float*)d_in[18];
    const float* em_bt = (const float*)d_in[19];
    const float* at_w  = (const float*)d_in[20];
    const float* at_b  = (const float*)d_in[21];
    const float* at_g  = (const float*)d_in[22];
    const float* at_bt = (const float*)d_in[23];
    const float* la_g  = (const float*)d_in[24];
    const float* la_bt = (const float*)d_in[25];

    char* ws = (char*)d_ws;
    auto al = [](size_t x) { return (x + 255) & ~(size_t)255; };
    size_t SZ_am   = (size_t)NB * 2 * IMP * 4;
    size_t SZ_G    = (size_t)MPAD * 768 * 2;
    size_t SZ_x    = (size_t)MPAD * 768 * 2;
    size_t SZ_xr2  = (size_t)ROWS * DIq * 2;
    size_t SZ_xi2  = (size_t)ROWS * DIq * 2;
    size_t SZ_de   = (size_t)ROWS * DIq * 4;
    size_t SZ_dbc  = (size_t)MPAD * 128 * 4;
    size_t SZ_ys   = (size_t)MPAD * DIq * 2;
    size_t SZ_sres = (size_t)ROWS * DIq * 2;
    size_t SZ_yem  = (size_t)MPAD * 1024 * 2;
    size_t SZ_pool = (size_t)NB * OUTq * 4;

    size_t o_am   = 0;
    size_t o_G    = al(o_am + SZ_am);
    size_t o_x    = al(o_G + SZ_G);
    size_t o_xr2  = al(o_x + SZ_x);
    size_t o_xi2  = al(o_xr2 + SZ_xr2);
    size_t o_de   = al(o_xi2 + SZ_xi2);
    size_t o_dbc  = al(o_de + SZ_de);
    size_t o_ys   = al(o_dbc + SZ_dbc);
    size_t o_sres = al(o_ys + SZ_ys);
    size_t o_yem  = al(o_sres + SZ_sres);
    size_t o_pool = al(o_yem + SZ_yem);

    size_t o_wpe  = al(o_pool + SZ_pool);
    size_t o_win0 = al(o_wpe  + (size_t)768 * 768 * 2);
    size_t o_win1 = al(o_win0 + (size_t)3072 * 768 * 2);
    size_t o_wot0 = al(o_win1 + (size_t)3072 * 768 * 2);
    size_t o_wot1 = al(o_wot0 + (size_t)768 * 1536 * 2);
    size_t o_wem  = al(o_wot1 + (size_t)768 * 1536 * 2);
    size_t o_wat  = al(o_wem  + (size_t)1024 * 768 * 2);
    size_t o_xpt  = al(o_wat  + (size_t)1024 * 1024 * 2);

    float* am    = (float*)(ws + o_am);
    unsigned short* G   = (unsigned short*)(ws + o_G);
    unsigned short* x   = (unsigned short*)(ws + o_x);
    unsigned short* xr2 = (unsigned short*)(ws + o_xr2);
    unsigned short* xi2b = (unsigned short*)(ws + o_xi2);
    float* de    = (float*)(ws + o_de);
    float* dbc128 = (float*)(ws + o_dbc);
    unsigned short* ys = (unsigned short*)(ws + o_ys);
    unsigned short* sresb = (unsigned short*)(ws + o_sres);
    unsigned short* yem = (unsigned short*)(ws + o_yem);
    float* pool  = (float*)(ws + o_pool);
    unsigned short* wpe  = (unsigned short*)(ws + o_wpe);
    unsigned short* win0 = (unsigned short*)(ws + o_win0);
    unsigned short* win1 = (unsigned short*)(ws + o_win1);
    unsigned short* wot0 = (unsigned short*)(ws + o_wot0);
    unsigned short* wot1 = (unsigned short*)(ws + o_wot1);
    unsigned short* wem  = (unsigned short*)(ws + o_wem);
    unsigned short* wat  = (unsigned short*)(ws + o_wat);
    unsigned short* xpt  = (unsigned short*)(ws + o_xpt);
    // head-phase overlays (bf16 now): t1 over de; t2 over xr2; gat over ys
    unsigned short* t1b  = (unsigned short*)(ws + o_de);
    unsigned short* t2b  = (unsigned short*)(ws + o_xr2);
    unsigned short* gatb = (unsigned short*)(ws + o_ys);

    k_transpose_all<<<10816, 256, 0, stream>>>(pe_w, in_w, ot_w, em_w, at_w, xp_w,
                                               wpe, win0, win1, wot0, wot1, wem, wat, xpt);

    int nq = NB * IMP / 4;
    k_avgmax<<<(nq + 255) / 256, 256, 0, stream>>>(img, am);
    k_gatepatch<<<(nq + 255) / 256, 256, 0, stream>>>(img, am, sa_w, G);

    dim3 blk(256);
    k_gemm_bf<EPI_POSEMB, true><<<dim3(12, 25), blk, 0, stream>>>(G, wpe, pe_b, x, 768, ROWS, 768, 768, pos);

    for (int l = 0; l < 2; l++) {
        const unsigned short* win = l ? win1 : win0;
        const unsigned short* wot = l ? wot1 : wot0;
        k_gemm_bf2<<<dim3(24, 25), blk, 0, stream>>>(x, win, in_b + l * 3072, xr2, sresb, ROWS, 768);
        int nc4 = ROWS * DIq / 4;
        k_conv_silu<<<(nc4 + 255) / 256, 256, 0, stream>>>(xr2, cv_w + (size_t)l * DIq * 4, cv_b + l * DIq, xi2b);
        k_gemm_bf<EPI_NONE, false><<<dim3(2, 25), blk, 0, stream>>>(xi2b, xpt + (size_t)l * 128 * 1536,
                                                                    nullptr, dbc128, 128, ROWS, 128, 1536, nullptr);
        k_dtred<<<ROWS / DT_RPB, 384, 0, stream>>>(dbc128, dt_w + (size_t)l * 48 * 1536, dt_b + l * 1536, de);
        k_scan<<<dim3(16, 48), blk, 0, stream>>>(de, xi2b, dbc128, sresb, Alog + (size_t)l * 1536 * 16,
                                                 Dv + l * 1536, ys);
        k_gemm_bf<EPI_NONE, true><<<dim3(12, 25), blk, 0, stream>>>(ys, wot, ot_b + l * 768, x, 768,
                                                                    ROWS, 768, 1536, nullptr);
    }

    // head (bf16 intermediates)
    k_gemm_bf<EPI_NONE, true><<<dim3(16, 25), blk, 0, stream>>>(x, wem, em_b, t1b, 1024, ROWS, 1024, 768, nullptr);
    k_ln_gelu<true, true><<<ROWS, 256, 0, stream>>>(t1b, em_g, em_bt, yem);
    k_gemm_bf<EPI_NONE, true><<<dim3(16, 25), blk, 0, stream>>>(yem, wat, at_b, t2b, 1024, ROWS, 1024, 1024, nullptr);
    k_ln_gelu<true, true><<<ROWS, 256, 0, stream>>>(t2b, at_g, at_bt, gatb);
    k_softpool<<<dim3(16, NB), 256, 0, stream>>>(gatb, yem, pool);
    k_final_ln<<<NB, 256, 0, stream>>>(pool, la_g, la_bt, (float*)d_out);
}